// Round 2
// baseline (898.141 us; speedup 1.0000x reference)
//
#include <hip/hip_runtime.h>
#include <hip/hip_bf16.h>

#define NB    128
#define CENC  2048
#define FIN   512
#define FHID  8
#define S2D   49
#define SO3D  455
#define NSO3  4000
#define HW    49

__device__ __forceinline__ int soff(int l) { return l*(4*l*l-1)/3; }  // sum_{l'<l}(2l'+1)^2

// ---------- generic fp32 GEMM: C[m,n] = alpha * sum_k A[m,k]*B[k,n], opt. relu, opt. split-K ----------
__global__ __launch_bounds__(256) void gemm_nn(
    const float* __restrict__ A, const float* __restrict__ B, float* __restrict__ C,
    int M, int N, int K, int lda, int ldb, int ldc,
    float alpha, int doRelu, int kPartLen)
{
  __shared__ float As[32*68];   // [kk][mm]
  __shared__ float Bs[32*68];   // [kk][nn]
  const int tid = threadIdx.x;
  const int tx = tid & 15, ty = tid >> 4;
  const int n0 = blockIdx.x * 64, m0 = blockIdx.y * 64;
  const int kStart = blockIdx.z * kPartLen;
  const int kEnd = min(K, kStart + kPartLen);
  C += (size_t)blockIdx.z * (size_t)M * (size_t)ldc;

  float acc[4][4] = {};
  for (int k0 = kStart; k0 < kEnd; k0 += 32) {
    {
      const int kk = tid & 31, mmB = tid >> 5;
      #pragma unroll
      for (int j = 0; j < 8; ++j) {
        const int mm = mmB + 8*j;
        const int m = m0 + mm, k = k0 + kk;
        As[kk*68 + mm] = (m < M && k < kEnd) ? A[(size_t)m*lda + k] : 0.f;
      }
    }
    {
      const int nn = tid & 63, kkB = tid >> 6;
      #pragma unroll
      for (int j = 0; j < 8; ++j) {
        const int kk = kkB + 4*j;
        const int n = n0 + nn, k = k0 + kk;
        Bs[kk*68 + nn] = (n < N && k < kEnd) ? B[(size_t)k*ldb + n] : 0.f;
      }
    }
    __syncthreads();
    #pragma unroll
    for (int kk = 0; kk < 32; ++kk) {
      const float4 a4 = *(const float4*)&As[kk*68 + ty*4];
      const float4 b4 = *(const float4*)&Bs[kk*68 + tx*4];
      const float av[4] = {a4.x,a4.y,a4.z,a4.w};
      const float bv[4] = {b4.x,b4.y,b4.z,b4.w};
      #pragma unroll
      for (int i = 0; i < 4; ++i)
        #pragma unroll
        for (int j = 0; j < 4; ++j)
          acc[i][j] = fmaf(av[i], bv[j], acc[i][j]);
    }
    __syncthreads();
  }
  #pragma unroll
  for (int i = 0; i < 4; ++i) {
    const int m = m0 + ty*4 + i;
    if (m >= M) continue;
    #pragma unroll
    for (int j = 0; j < 4; ++j) {
      const int n = n0 + tx*4 + j;
      if (n >= N) continue;
      float v = acc[i][j] * alpha;
      if (doRelu) v = fmaxf(v, 0.f);
      C[(size_t)m*ldc + n] = v;
    }
  }
}

// ---------- conv (bchw,fc->bfhw) fused with P projection (hw,i): writes x3[b,f,i] ----------
// grid: (FIN/64, NB). block 256. tile: 64 f x 49 hw (padded 64), K-chunks of 32 over CENC.
__global__ __launch_bounds__(256) void conv_proj(
    const float* __restrict__ fmap, const float* __restrict__ convw,
    const float* __restrict__ convb, const float* __restrict__ P,
    float* __restrict__ x3)
{
  __shared__ float smem[32*68 + 32*64];  // As[32][68] | Bs[32][64]; aliased as X1s[49][64] in epilogue
  __shared__ float Ps[49*52];            // [hw][i], i padded to 52
  float* As = smem;
  float* Bs = smem + 32*68;
  float* X1s = smem;                     // 49*64 = 3136 <= 4224 floats
  const int tid = threadIdx.x;
  const int b  = blockIdx.y;
  const int f0 = blockIdx.x * 64;

  for (int idx = tid; idx < 49*49; idx += 256) {
    const int hw = idx / 49, i = idx - hw*49;
    Ps[hw*52 + i] = P[idx];
  }

  const int tx = tid & 15, ty = tid >> 4;   // tx -> hw group (active tx<13), ty -> f group
  float acc[4][4] = {};
  const float* fb = fmap + (size_t)b * CENC * HW;

  for (int c0 = 0; c0 < CENC; c0 += 32) {
    {
      const int kk = tid & 31, ffB = tid >> 5;
      #pragma unroll
      for (int j = 0; j < 8; ++j) {
        const int ff = ffB + 8*j;
        As[kk*68 + ff] = convw[(size_t)(f0+ff)*CENC + c0 + kk];
      }
    }
    {
      #pragma unroll
      for (int j = 0; j < 7; ++j) {
        const int idx = tid + 256*j;
        if (idx < 32*49) {
          const int kk = idx / 49, hw = idx - kk*49;
          Bs[kk*64 + hw] = fb[(size_t)(c0+kk)*HW + hw];
        }
      }
    }
    __syncthreads();
    #pragma unroll
    for (int kk = 0; kk < 32; ++kk) {
      const float4 a4 = *(const float4*)&As[kk*68 + ty*4];
      const float4 b4 = *(const float4*)&Bs[kk*64 + tx*4];
      const float av[4] = {a4.x,a4.y,a4.z,a4.w};
      const float bv[4] = {b4.x,b4.y,b4.z,b4.w};
      #pragma unroll
      for (int i = 0; i < 4; ++i)
        #pragma unroll
        for (int j = 0; j < 4; ++j)
          acc[i][j] = fmaf(av[i], bv[j], acc[i][j]);
    }
    __syncthreads();
  }

  // epilogue: X1 tile (+bias) -> LDS, then multiply by P (49x49) and store x3
  float cb[4];
  #pragma unroll
  for (int i = 0; i < 4; ++i) cb[i] = convb[f0 + ty*4 + i];
  #pragma unroll
  for (int j = 0; j < 4; ++j) {
    const int hw = tx*4 + j;
    if (hw < 49) {
      #pragma unroll
      for (int i = 0; i < 4; ++i)
        X1s[hw*64 + ty*4 + i] = acc[i][j] + cb[i];
    }
  }
  __syncthreads();
  for (int idx = tid; idx < 64*49; idx += 256) {
    const int fl = idx / 49, i = idx - fl*49;
    float s = 0.f;
    #pragma unroll 7
    for (int hw = 0; hw < 49; ++hw)
      s = fmaf(X1s[hw*64 + fl], Ps[hw*52 + i], s);
    x3[((size_t)b*FIN + f0 + fl)*S2D + i] = s;
  }
}

// ---------- s2 -> so3 linear: y[b,g,l,u,m] = 1/sqrt(512) * sum_f x3[b,f,l^2+m] * psi[f,g,l^2+u] ----------
// grid: (7 [l], 32 [b-groups of 4]). block 256. thread owns (b_local, u, m_half), loops g in regs.
__global__ __launch_bounds__(256) void s2_to_so3(
    const float* __restrict__ x3, const float* __restrict__ psi, float* __restrict__ y)
{
  __shared__ float Xs[4*32*16];   // [b_l][f_l][m(16)]
  __shared__ float Ps[32*8*16];   // [f_l][g][u(16)]
  const int tid = threadIdx.x;
  const int l = blockIdx.x;
  const int d = 2*l + 1;
  const int s2o = l*l;
  const int so = soff(l);
  const int b0 = blockIdx.y * 4;
  const int mhCnt = (d + 7) / 8;          // 1 or 2
  const int T = 4 * d * mhCnt;            // triples
  const bool valid = tid < T;
  int tb = 0, tu = 0, tmh = 0;
  if (valid) {
    tb = tid / (d*mhCnt);
    const int r = tid - tb*(d*mhCnt);
    tu = r / mhCnt;
    tmh = r - tu*mhCnt;
  }

  float acc[8][8] = {};
  const float invSqF = 0.044194173824159216f;  // 1/sqrt(512)

  for (int fc = 0; fc < FIN; fc += 32) {
    const int totX = 4*32*d;
    for (int idx = tid; idx < totX; idx += 256) {
      const int bl = idx / (32*d);
      const int r = idx - bl*(32*d);
      const int fl = r / d;
      const int m = r - fl*d;
      Xs[(bl*32 + fl)*16 + m] = x3[((size_t)(b0+bl)*FIN + fc + fl)*S2D + s2o + m];
    }
    const int totP = 32*8*d;
    for (int idx = tid; idx < totP; idx += 256) {
      const int fl = idx / (8*d);
      const int r = idx - fl*(8*d);
      const int g = r / d;
      const int u = r - g*d;
      Ps[(fl*8 + g)*16 + u] = psi[((size_t)(fc+fl)*8 + g)*S2D + s2o + u];
    }
    __syncthreads();
    if (valid) {
      for (int fl = 0; fl < 32; ++fl) {
        const float4 xa = *(const float4*)&Xs[(tb*32 + fl)*16 + tmh*8];
        const float4 xb = *(const float4*)&Xs[(tb*32 + fl)*16 + tmh*8 + 4];
        const float xv[8] = {xa.x,xa.y,xa.z,xa.w,xb.x,xb.y,xb.z,xb.w};
        #pragma unroll
        for (int g = 0; g < 8; ++g) {
          const float pv = Ps[(fl*8 + g)*16 + tu];
          #pragma unroll
          for (int mm = 0; mm < 8; ++mm)
            acc[g][mm] = fmaf(pv, xv[mm], acc[g][mm]);
        }
      }
    }
    __syncthreads();
  }

  if (valid) {
    #pragma unroll
    for (int g = 0; g < 8; ++g) {
      for (int mm = 0; mm < 8; ++mm) {
        const int m = tmh*8 + mm;
        if (m < d)
          y[((size_t)(b0+tb)*FHID + g)*SO3D + so + tu*d + m] = acc[g][mm] * invSqF;
      }
    }
  }
}

// ---------- final so3 conv: out[b, so+v*d+m] = 1/sqrt(8d) * sum_{f,u} z[b,f,so+u*d+m]*psi2[f,so+u*d+v] ----------
// NOTE: output dtype is fp32 (all-fp32 reference; R0 failure signature showed no bf16 ulp-floor in threshold).
__global__ __launch_bounds__(512) void so3_final(
    const float* __restrict__ zpart, const float* __restrict__ psi2,
    float* __restrict__ out)
{
  __shared__ float Zs[8*SO3D];
  __shared__ float P2s[8*SO3D];
  const int b = blockIdx.x, tid = threadIdx.x;
  for (int idx = tid; idx < 8*SO3D; idx += 512) {
    const int f = idx / SO3D, i = idx - f*SO3D;
    float s = 0.f;
    #pragma unroll
    for (int p = 0; p < 4; ++p)
      s += zpart[((size_t)p*(NB*FHID) + (size_t)b*FHID + f)*SO3D + i];
    Zs[idx] = s;
    P2s[idx] = psi2[idx];
  }
  __syncthreads();
  if (tid < SO3D) {
    const int i = tid;
    int l;
    if (i < 1) l = 0; else if (i < 10) l = 1; else if (i < 35) l = 2;
    else if (i < 84) l = 3; else if (i < 165) l = 4; else if (i < 286) l = 5; else l = 6;
    const int so = soff(l), d = 2*l+1;
    const int r = i - so;
    const int v = r / d, m = r - v*d;
    float acc = 0.f;
    for (int f = 0; f < 8; ++f)
      for (int u = 0; u < d; ++u)
        acc = fmaf(Zs[f*SO3D + so + u*d + m], P2s[f*SO3D + so + u*d + v], acc);
    const float scale = rsqrtf(8.0f * (float)d);
    out[(size_t)b*SO3D + i] = acc * scale;
  }
}

extern "C" void kernel_launch(void* const* d_in, const int* in_sizes, int n_in,
                              void* d_out, int out_size, void* d_ws, size_t ws_size,
                              hipStream_t stream) {
  const float* fmap    = (const float*)d_in[0];
  const float* conv_w  = (const float*)d_in[1];
  const float* conv_b  = (const float*)d_in[2];
  const float* proj_w  = (const float*)d_in[3];
  const float* proj_Y  = (const float*)d_in[4];
  const float* fs_w    = (const float*)d_in[5];
  const float* fs_Y    = (const float*)d_in[6];
  const float* act_to  = (const float*)d_in[7];
  const float* act_from= (const float*)d_in[8];
  const float* so3_w   = (const float*)d_in[9];
  const float* so3_D   = (const float*)d_in[10];
  float* out           = (float*)d_out;

  // Compact workspace layout (floats), total 7,981,056 floats = 31.9 MB.
  // Lifetimes: wX3 dead after s2_to_so3 -> wZ aliases into wX3's region.
  float* ws = (float*)d_ws;
  float* wP    = ws;            // 49*49            [0, 2560)
  float* wPsi  = ws + 2560;     // 4096*49          [2560, 203776)
  float* wPsi2 = ws + 203776;   // 8*455            [203776, 207872)
  float* wG    = ws + 207872;   // 1024*4000        [207872, 4303872)
  float* wX3   = ws + 4303872;  // 128*512*49       [4303872, 7515136)
  float* wY    = ws + 7515136;  // 1024*455         [7515136, 7981056)
  float* wZ    = ws + 4303872;  // 4*1024*455=1863680, aliases dead wX3 region

  const float is192 = 0.07216878364870323f;  // 1/sqrt(192)

  // P = proj_w(49x192) @ proj_Y(192x49) / sqrt(192)
  gemm_nn<<<dim3(1,1,1), 256, 0, stream>>>(proj_w, proj_Y, wP, 49,49,192, 192,49,49, is192, 0, 192);
  // psi = fs_w(4096x192) @ fs_Y(192x49) / sqrt(192)
  gemm_nn<<<dim3(1,64,1), 256, 0, stream>>>(fs_w, fs_Y, wPsi, 4096,49,192, 192,49,49, is192, 0, 192);
  // psi2 = so3_w(8x192) @ so3_D(192x455) / sqrt(192)
  gemm_nn<<<dim3(8,1,1), 256, 0, stream>>>(so3_w, so3_D, wPsi2, 8,455,192, 192,455,455, is192, 0, 192);
  // x3[b,f,i] = (conv_w @ fmap_b + conv_b) @ P
  conv_proj<<<dim3(8,128), 256, 0, stream>>>(fmap, conv_w, conv_b, wP, wX3);
  // y[b,g,:] = s2->so3 linear
  s2_to_so3<<<dim3(7,32), 256, 0, stream>>>(wX3, wPsi, wY);
  // g = relu(y(1024x455) @ act_to(455x4000))
  gemm_nn<<<dim3(63,16,1), 256, 0, stream>>>(wY, act_to, wG, 1024,4000,455, 455,4000,4000, 1.f, 1, 455);
  // z partials = g(1024x4000) @ act_from(4000x455), split-K=4
  gemm_nn<<<dim3(8,16,4), 256, 0, stream>>>(wG, act_from, wZ, 1024,455,4000, 4000,455,455, 1.f, 0, 1000);
  // final so3 conv + partial-sum + fp32 store
  so3_final<<<dim3(128), 512, 0, stream>>>(wZ, wPsi2, out);
}

// Round 3
// 767.721 us; speedup vs baseline: 1.1699x; 1.1699x over previous
//
#include <hip/hip_runtime.h>
#include <hip/hip_bf16.h>

#define NB    128
#define CENC  2048
#define FIN   512
#define FHID  8
#define S2D   49
#define SO3D  455
#define HW    49

typedef unsigned short ushort_t;
typedef __bf16 bf16x8 __attribute__((ext_vector_type(8)));
typedef float  f32x4  __attribute__((ext_vector_type(4)));

__device__ __forceinline__ int soff(int l) { return l*(4*l*l-1)/3; }

__device__ __forceinline__ ushort_t f2bf(float x) {
  __hip_bfloat16 h = __float2bfloat16(x);
  return *reinterpret_cast<ushort_t*>(&h);
}

// ---------- small fp32 GEMM (prep only): C = alpha * A@B ----------
__global__ __launch_bounds__(256) void gemm_nn(
    const float* __restrict__ A, const float* __restrict__ B, float* __restrict__ C,
    int M, int N, int K, int lda, int ldb, int ldc, float alpha)
{
  __shared__ float As[32*68];
  __shared__ float Bs[32*68];
  const int tid = threadIdx.x;
  const int tx = tid & 15, ty = tid >> 4;
  const int n0 = blockIdx.x * 64, m0 = blockIdx.y * 64;
  float acc[4][4] = {};
  for (int k0 = 0; k0 < K; k0 += 32) {
    {
      const int kk = tid & 31, mmB = tid >> 5;
      #pragma unroll
      for (int j = 0; j < 8; ++j) {
        const int mm = mmB + 8*j;
        const int m = m0 + mm, k = k0 + kk;
        As[kk*68 + mm] = (m < M && k < K) ? A[(size_t)m*lda + k] : 0.f;
      }
    }
    {
      const int nn = tid & 63, kkB = tid >> 6;
      #pragma unroll
      for (int j = 0; j < 8; ++j) {
        const int kk = kkB + 4*j;
        const int n = n0 + nn, k = k0 + kk;
        Bs[kk*68 + nn] = (n < N && k < K) ? B[(size_t)k*ldb + n] : 0.f;
      }
    }
    __syncthreads();
    #pragma unroll
    for (int kk = 0; kk < 32; ++kk) {
      const float4 a4 = *(const float4*)&As[kk*68 + ty*4];
      const float4 b4 = *(const float4*)&Bs[kk*68 + tx*4];
      const float av[4] = {a4.x,a4.y,a4.z,a4.w};
      const float bv[4] = {b4.x,b4.y,b4.z,b4.w};
      #pragma unroll
      for (int i = 0; i < 4; ++i)
        #pragma unroll
        for (int j = 0; j < 4; ++j)
          acc[i][j] = fmaf(av[i], bv[j], acc[i][j]);
    }
    __syncthreads();
  }
  #pragma unroll
  for (int i = 0; i < 4; ++i) {
    const int m = m0 + ty*4 + i;
    if (m >= M) continue;
    #pragma unroll
    for (int j = 0; j < 4; ++j) {
      const int n = n0 + tx*4 + j;
      if (n >= N) continue;
      C[(size_t)m*ldc + n] = acc[i][j] * alpha;
    }
  }
}

// ---------- fp32 -> bf16 elementwise (conv_w) ----------
__global__ void cvt_bf16(const float* __restrict__ in, ushort_t* __restrict__ out, int n4) {
  int i = (blockIdx.x*256 + threadIdx.x)*4;
  if (i < n4) {
    float4 v = *(const float4*)&in[i];
    out[i+0] = f2bf(v.x); out[i+1] = f2bf(v.y);
    out[i+2] = f2bf(v.z); out[i+3] = f2bf(v.w);
  }
}

// ---------- transpose + cvt + pad: in fp32 [R][C] -> out bf16 [Cp][Rp] (zeros outside) ----------
__global__ __launch_bounds__(256) void transpose_cvt(
    const float* __restrict__ in, int R, int C,
    ushort_t* __restrict__ out, int Rp, int Cp)
{
  __shared__ float t[32][33];
  const int c0 = blockIdx.x*32, r0 = blockIdx.y*32;
  const int tx = threadIdx.x & 31, ty = threadIdx.x >> 5;
  #pragma unroll
  for (int j = 0; j < 4; ++j) {
    const int r = r0 + ty + j*8, c = c0 + tx;
    t[ty + j*8][tx] = (r < R && c < C) ? in[(size_t)r*C + c] : 0.f;
  }
  __syncthreads();
  #pragma unroll
  for (int j = 0; j < 4; ++j) {
    const int c = c0 + ty + j*8, r = r0 + tx;
    if (c < Cp && r < Rp) out[(size_t)c*Rp + r] = f2bf(t[tx][ty + j*8]);
  }
}

// ---------- fmapPT[b][i(64)][c] = bf16( sum_hw fmap[b,c,hw] * P[hw,i] ), i>=49 -> 0 ----------
// also block(0,0) writes sumP[i] = sum_hw P[hw,i] (0 for i>=49). grid(8, 128), block 256.
__global__ __launch_bounds__(256) void prep_fmapPT(
    const float* __restrict__ fmap, const float* __restrict__ P,
    float* __restrict__ sumP, ushort_t* __restrict__ out)
{
  __shared__ float Ps[49*49];
  const int tid = threadIdx.x;
  const int b = blockIdx.y, cc = blockIdx.x;
  for (int i = tid; i < 2401; i += 256) Ps[i] = P[i];
  __syncthreads();
  if (b == 0 && cc == 0 && tid < 64) {
    float s = 0.f;
    if (tid < 49) for (int hw = 0; hw < 49; ++hw) s += Ps[hw*49 + tid];
    sumP[tid] = (tid < 49) ? s : 0.f;
  }
  const int c = cc*256 + tid;
  float fm[49];
  const float* fp = fmap + ((size_t)b*CENC + c)*HW;
  #pragma unroll
  for (int h = 0; h < 49; ++h) fm[h] = fp[h];
  ushort_t* op = out + (size_t)b*64*CENC + c;
  for (int i = 0; i < 49; ++i) {
    float s = 0.f;
    #pragma unroll 7
    for (int hw = 0; hw < 49; ++hw) s = fmaf(fm[hw], Ps[hw*49 + i], s);
    op[(size_t)i*CENC] = f2bf(s);
  }
  #pragma unroll
  for (int i = 49; i < 64; ++i) op[(size_t)i*CENC] = 0;
}

// ---------- bf16 MFMA NT GEMM: C[m,n] = sum_k A[m,k]*B[n,k] ----------
// A bf16 [M][lda], B bf16 [N][ldb] (pre-transposed), 128x128 tile, BK=64, 4 waves.
// mode 0: fp32 store, optional rank-1 bias biasRow[m]*biasCol[n&63]
// mode 1: relu -> bf16 store
// mode 2: split-K fp32 partial (blockIdx.z, kPartLen), plain store
#define LSTR 72
__global__ __launch_bounds__(256, 2) void gemm_bf16_nt(
    const ushort_t* __restrict__ A, const ushort_t* __restrict__ B, void* __restrict__ Cv,
    int M, int N, int K, int lda, int ldb, int ldc,
    int mode, const float* __restrict__ biasRow, const float* __restrict__ biasCol,
    int kPartLen)
{
  __shared__ ushort_t Alds[128*LSTR];
  __shared__ ushort_t Blds[128*LSTR];
  const int tid  = threadIdx.x;
  const int wave = tid >> 6, lane = tid & 63;
  const int wm = wave >> 1, wn = wave & 1;
  const int col = lane & 15, quad = lane >> 4;
  const int m0 = blockIdx.y * 128, n0 = blockIdx.x * 128;
  int kStart = 0, kEnd = K;
  float*    C  = (float*)Cv;
  ushort_t* Cb = (ushort_t*)Cv;
  if (mode == 2) {
    kStart = blockIdx.z * kPartLen;
    kEnd = min(K, kStart + kPartLen);
    C += (size_t)blockIdx.z * (size_t)M * (size_t)ldc;
  }

  f32x4 acc[4][4];
  #pragma unroll
  for (int i = 0; i < 4; ++i)
    #pragma unroll
    for (int j = 0; j < 4; ++j)
      acc[i][j] = (f32x4){0.f,0.f,0.f,0.f};

  for (int k0 = kStart; k0 < kEnd; k0 += 64) {
    #pragma unroll
    for (int r = 0; r < 4; ++r) {
      const int u = tid + 256*r;
      const int mm = u >> 3, kg = u & 7;
      *(uint4*)&Alds[mm*LSTR + kg*8] = *(const uint4*)&A[(size_t)(m0+mm)*lda + k0 + kg*8];
      *(uint4*)&Blds[mm*LSTR + kg*8] = *(const uint4*)&B[(size_t)(n0+mm)*ldb + k0 + kg*8];
    }
    __syncthreads();
    #pragma unroll
    for (int ks = 0; ks < 2; ++ks) {
      bf16x8 af[4], bfr[4];
      #pragma unroll
      for (int t = 0; t < 4; ++t) {
        af[t]  = *(bf16x8*)&Alds[(wm*64 + t*16 + col)*LSTR + ks*32 + quad*8];
        bfr[t] = *(bf16x8*)&Blds[(wn*64 + t*16 + col)*LSTR + ks*32 + quad*8];
      }
      #pragma unroll
      for (int i = 0; i < 4; ++i)
        #pragma unroll
        for (int j = 0; j < 4; ++j)
          acc[i][j] = __builtin_amdgcn_mfma_f32_16x16x32_bf16(af[i], bfr[j], acc[i][j], 0, 0, 0);
    }
    __syncthreads();
  }

  // epilogue: C/D layout col = lane&15, row = quad*4 + reg
  #pragma unroll
  for (int i = 0; i < 4; ++i) {
    const int mBase = m0 + wm*64 + i*16 + quad*4;
    #pragma unroll
    for (int j = 0; j < 4; ++j) {
      const int n = n0 + wn*64 + j*16 + col;
      if (mode == 1) {
        #pragma unroll
        for (int r = 0; r < 4; ++r)
          Cb[(size_t)(mBase+r)*ldc + n] = f2bf(fmaxf(acc[i][j][r], 0.f));
      } else if (biasRow) {
        const float bc = biasCol[n & 63];
        #pragma unroll
        for (int r = 0; r < 4; ++r)
          C[(size_t)(mBase+r)*ldc + n] = acc[i][j][r] + biasRow[mBase+r]*bc;
      } else {
        #pragma unroll
        for (int r = 0; r < 4; ++r)
          C[(size_t)(mBase+r)*ldc + n] = acc[i][j][r];
      }
    }
  }
}

// ---------- zero y_pad columns [455,512) ----------
__global__ void zero_ypad(ushort_t* __restrict__ y) {
  const int idx = blockIdx.x*256 + threadIdx.x;
  if (idx < 1024*57) {
    const int r = idx / 57, c = 455 + idx % 57;
    y[r*512 + c] = 0;
  }
}

// ---------- s2 -> so3 linear (reads x3T fp32 [512][8192], writes y_pad bf16 [1024][512]) ----------
__global__ __launch_bounds__(256) void s2_to_so3(
    const float* __restrict__ x3T, const float* __restrict__ psi, ushort_t* __restrict__ y)
{
  __shared__ float Xs[4*32*16];
  __shared__ float Ps[32*8*16];
  const int tid = threadIdx.x;
  const int l = blockIdx.x;
  const int d = 2*l + 1;
  const int s2o = l*l;
  const int so = soff(l);
  const int b0 = blockIdx.y * 4;
  const int mhCnt = (d + 7) / 8;
  const int T = 4 * d * mhCnt;
  const bool valid = tid < T;
  int tb = 0, tu = 0, tmh = 0;
  if (valid) {
    tb = tid / (d*mhCnt);
    const int r = tid - tb*(d*mhCnt);
    tu = r / mhCnt;
    tmh = r - tu*mhCnt;
  }

  float acc[8][8] = {};
  const float invSqF = 0.044194173824159216f;  // 1/sqrt(512)

  for (int fc = 0; fc < FIN; fc += 32) {
    const int totX = 4*32*d;
    for (int idx = tid; idx < totX; idx += 256) {
      const int bl = idx / (32*d);
      const int r = idx - bl*(32*d);
      const int fl = r / d;
      const int m = r - fl*d;
      Xs[(bl*32 + fl)*16 + m] = x3T[(size_t)(fc+fl)*8192 + (b0+bl)*64 + s2o + m];
    }
    const int totP = 32*8*d;
    for (int idx = tid; idx < totP; idx += 256) {
      const int fl = idx / (8*d);
      const int r = idx - fl*(8*d);
      const int g = r / d;
      const int u = r - g*d;
      Ps[(fl*8 + g)*16 + u] = psi[((size_t)(fc+fl)*8 + g)*S2D + s2o + u];
    }
    __syncthreads();
    if (valid) {
      for (int fl = 0; fl < 32; ++fl) {
        const float4 xa = *(const float4*)&Xs[(tb*32 + fl)*16 + tmh*8];
        const float4 xb = *(const float4*)&Xs[(tb*32 + fl)*16 + tmh*8 + 4];
        const float xv[8] = {xa.x,xa.y,xa.z,xa.w,xb.x,xb.y,xb.z,xb.w};
        #pragma unroll
        for (int g = 0; g < 8; ++g) {
          const float pv = Ps[(fl*8 + g)*16 + tu];
          #pragma unroll
          for (int mm = 0; mm < 8; ++mm)
            acc[g][mm] = fmaf(pv, xv[mm], acc[g][mm]);
        }
      }
    }
    __syncthreads();
  }

  if (valid) {
    #pragma unroll
    for (int g = 0; g < 8; ++g) {
      for (int mm = 0; mm < 8; ++mm) {
        const int m = tmh*8 + mm;
        if (m < d)
          y[((size_t)(b0+tb)*8 + g)*512 + so + tu*d + m] = f2bf(acc[g][mm] * invSqF);
      }
    }
  }
}

// ---------- final so3 conv: 8-partial sum + per-l contraction + fp32 store ----------
__global__ __launch_bounds__(512) void so3_final(
    const float* __restrict__ zpart, const float* __restrict__ psi2,
    float* __restrict__ out)
{
  __shared__ float Zs[8*SO3D];
  __shared__ float P2s[8*SO3D];
  const int b = blockIdx.x, tid = threadIdx.x;
  for (int idx = tid; idx < 8*SO3D; idx += 512) {
    const int f = idx / SO3D, i = idx - f*SO3D;
    float s = 0.f;
    #pragma unroll
    for (int p = 0; p < 8; ++p)
      s += zpart[((size_t)p*1024 + (size_t)b*FHID + f)*512 + i];
    Zs[idx] = s;
    P2s[idx] = psi2[idx];
  }
  __syncthreads();
  if (tid < SO3D) {
    const int i = tid;
    int l;
    if (i < 1) l = 0; else if (i < 10) l = 1; else if (i < 35) l = 2;
    else if (i < 84) l = 3; else if (i < 165) l = 4; else if (i < 286) l = 5; else l = 6;
    const int so = soff(l), d = 2*l+1;
    const int r = i - so;
    const int v = r / d, m = r - v*d;
    float acc = 0.f;
    for (int f = 0; f < 8; ++f)
      for (int u = 0; u < d; ++u)
        acc = fmaf(Zs[f*SO3D + so + u*d + m], P2s[f*SO3D + so + u*d + v], acc);
    const float scale = rsqrtf(8.0f * (float)d);
    out[(size_t)b*SO3D + i] = acc * scale;
  }
}

extern "C" void kernel_launch(void* const* d_in, const int* in_sizes, int n_in,
                              void* d_out, int out_size, void* d_ws, size_t ws_size,
                              hipStream_t stream) {
  const float* fmap    = (const float*)d_in[0];
  const float* conv_w  = (const float*)d_in[1];
  const float* conv_b  = (const float*)d_in[2];
  const float* proj_w  = (const float*)d_in[3];
  const float* proj_Y  = (const float*)d_in[4];
  const float* fs_w    = (const float*)d_in[5];
  const float* fs_Y    = (const float*)d_in[6];
  const float* act_to  = (const float*)d_in[7];
  const float* act_from= (const float*)d_in[8];
  const float* so3_w   = (const float*)d_in[9];
  const float* so3_D   = (const float*)d_in[10];
  float* out           = (float*)d_out;

  // byte-offset workspace layout (aliasing by lifetime), total ~59.8 MB
  char* wsb = (char*)d_ws;
  float*    wP       = (float*)(wsb + 0);          //  49x49 fp32
  float*    wSumP    = (float*)(wsb + 9728);       //  64 fp32
  float*    wPsi     = (float*)(wsb + 9984);       //  4096x49 fp32
  float*    wPsi2    = (float*)(wsb + 812800);     //  8x455 fp32
  ushort_t* cwB      = (ushort_t*)(wsb + 827392);  //  512x2048 bf16
  ushort_t* actToT   = (ushort_t*)(wsb + 2924544); //  4096x512 bf16
  ushort_t* actFromT = (ushort_t*)(wsb + 7118848); //  512x4096 bf16
  ushort_t* yPad     = (ushort_t*)(wsb + 11313152);//  1024x512 bf16
  ushort_t* fmapPT   = (ushort_t*)(wsb + 12361728);//  8192x2048 bf16 (dead after conv gemm)
  float*    zPart    = (float*)(wsb + 12361728);   //  8x1024x512 fp32, aliases fmapPT
  float*    wX3T     = (float*)(wsb + 45916160);   //  512x8192 fp32 (dead after s2_to_so3)
  ushort_t* gBuf     = (ushort_t*)(wsb + 45916160);//  1024x4096 bf16, aliases wX3T

  const float is192 = 0.07216878364870323f;  // 1/sqrt(192)

  // prep (fp32 smalls + bf16 conversions)
  gemm_nn<<<dim3(1,1), 256, 0, stream>>>(proj_w, proj_Y, wP, 49,49,192, 192,49,49, is192);
  gemm_nn<<<dim3(1,64), 256, 0, stream>>>(fs_w, fs_Y, wPsi, 4096,49,192, 192,49,49, is192);
  gemm_nn<<<dim3(8,1), 256, 0, stream>>>(so3_w, so3_D, wPsi2, 8,455,192, 192,455,455, is192);
  cvt_bf16<<<dim3(1024), 256, 0, stream>>>(conv_w, cwB, 512*2048);
  transpose_cvt<<<dim3(128,16), 256, 0, stream>>>(act_to, 455, 4000, actToT, 512, 4096);
  transpose_cvt<<<dim3(16,128), 256, 0, stream>>>(act_from, 4000, 455, actFromT, 4096, 512);
  prep_fmapPT<<<dim3(8,128), 256, 0, stream>>>(fmap, wP, wSumP, fmapPT);
  zero_ypad<<<dim3(228), 256, 0, stream>>>(yPad);

  // x3T[f][(b,i)] = cwB @ fmapPT^T + conv_b[f]*sumP[i]   (M=512, N=8192, K=2048)
  gemm_bf16_nt<<<dim3(64,4), 256, 0, stream>>>(cwB, fmapPT, wX3T,
      512, 8192, 2048, 2048, 2048, 8192, 0, conv_b, wSumP, 0);
  // y = s2->so3 linear (bf16 out into yPad)
  s2_to_so3<<<dim3(7,32), 256, 0, stream>>>(wX3T, wPsi, yPad);
  // g = relu(yPad @ actToT^T) bf16   (M=1024, N=4096, K=512)
  gemm_bf16_nt<<<dim3(32,8), 256, 0, stream>>>(yPad, actToT, gBuf,
      1024, 4096, 512, 512, 512, 4096, 1, nullptr, nullptr, 0);
  // zPart = g @ actFromT^T, split-K=8   (M=1024, N=512, K=4096)
  gemm_bf16_nt<<<dim3(4,8,8), 256, 0, stream>>>(gBuf, actFromT, zPart,
      1024, 512, 4096, 4096, 4096, 512, 2, nullptr, nullptr, 512);
  // final contraction + fp32 store
  so3_final<<<dim3(128), 512, 0, stream>>>(zPart, wPsi2, out);
}